// Round 1
// baseline (7901.243 us; speedup 1.0000x reference)
//
#include <hip/hip_runtime.h>

#define CDIV(a, b) (((a) + (b) - 1) / (b))

// ---------------------------------------------------------------------------
// conv 3x3, pad 1, stride {1,2} + bias + PReLU. One block handles a 256-wide
// spatial strip of one (b, co); weights for that co staged in LDS.
// ---------------------------------------------------------------------------
__global__ void conv3x3_prelu_kernel(const float* __restrict__ in,
                                     const float* __restrict__ wgt,
                                     const float* __restrict__ bias,
                                     const float* __restrict__ alpha,
                                     float* __restrict__ out,
                                     int Ci, int Hi, int Wi,
                                     int Co, int Ho, int Wo, int stride) {
    extern __shared__ float sw[];  // Ci * 9 floats
    const int co = blockIdx.y;
    const int b  = blockIdx.z;
    const int nW = Ci * 9;
    for (int i = threadIdx.x; i < nW; i += blockDim.x)
        sw[i] = wgt[(size_t)co * nW + i];
    __syncthreads();

    const int sp = blockIdx.x * blockDim.x + threadIdx.x;
    if (sp >= Ho * Wo) return;
    const int ho = sp / Wo;
    const int wo = sp - ho * Wo;
    const int iy0 = ho * stride - 1;
    const int ix0 = wo * stride - 1;

    float acc = bias[co];
    const float* inb = in + (size_t)b * Ci * Hi * Wi;
    for (int ci = 0; ci < Ci; ++ci) {
        const float* inc = inb + (size_t)ci * Hi * Wi;
        const float* wc  = sw + ci * 9;
#pragma unroll
        for (int kh = 0; kh < 3; ++kh) {
            const int iy = iy0 + kh;
            if (iy < 0 || iy >= Hi) continue;
            const float* row = inc + (size_t)iy * Wi;
#pragma unroll
            for (int kw = 0; kw < 3; ++kw) {
                const int ix = ix0 + kw;
                if (ix < 0 || ix >= Wi) continue;
                acc += row[ix] * wc[kh * 3 + kw];
            }
        }
    }
    const float a = alpha[co];
    const float v = acc >= 0.f ? acc : a * acc;
    out[(((size_t)b * Co + co) * Ho + ho) * Wo + wo] = v;
}

// ---------------------------------------------------------------------------
// flow halving: 2x2 mean * 0.5  == sum * 0.125.  in [B*2,Hi,Wi] -> out half res
// ---------------------------------------------------------------------------
__global__ void halve_flow_kernel(const float* __restrict__ in,
                                  float* __restrict__ out,
                                  int BC, int Ho, int Wo, int Hi, int Wi) {
    const int idx = blockIdx.x * blockDim.x + threadIdx.x;
    const int total = BC * Ho * Wo;
    if (idx >= total) return;
    const int wo = idx % Wo;
    int t = idx / Wo;
    const int ho = t % Ho;
    const int bc = t / Ho;
    const float* p = in + ((size_t)bc * Hi + 2 * ho) * Wi + 2 * wo;
    const float s = p[0] + p[1] + p[Wi] + p[Wi + 1];
    out[idx] = s * 0.125f;
}

// ---------------------------------------------------------------------------
// bilinear forward splat (scatter-add) of feat + a ones channel (cnt).
// One thread per source pixel; loops channels.
// ---------------------------------------------------------------------------
__global__ void splat_kernel(const float* __restrict__ feat,
                             const float* __restrict__ flow,
                             float* __restrict__ num,
                             float* __restrict__ cnt,
                             int B, int C, int H, int W) {
    const int HW = H * W;
    const int idx = blockIdx.x * blockDim.x + threadIdx.x;
    if (idx >= B * HW) return;
    const int x = idx % W;
    int t = idx / W;
    const int y = t % H;
    const int b = t / H;

    const float* fl = flow + (size_t)b * 2 * HW;
    const float fx = fl[y * W + x] + (float)x;
    const float fy = fl[HW + y * W + x] + (float)y;
    const float x0f = floorf(fx), y0f = floorf(fy);
    const int x0 = (int)x0f, y0 = (int)y0f;
    const int x1 = x0 + 1, y1 = y0 + 1;
    const float ax = fx - x0f, ay = fy - y0f;
    const float w00 = (1.f - ax) * (1.f - ay);
    const float w10 = ax * (1.f - ay);
    const float w01 = (1.f - ax) * ay;
    const float w11 = ax * ay;
    const bool vx0 = (x0 >= 0) && (x0 < W);
    const bool vx1 = (x1 >= 0) && (x1 < W);
    const bool vy0 = (y0 >= 0) && (y0 < H);
    const bool vy1 = (y1 >= 0) && (y1 < H);
    const bool v00 = vx0 && vy0, v10 = vx1 && vy0;
    const bool v01 = vx0 && vy1, v11 = vx1 && vy1;
    const int i00 = y0 * W + x0, i10 = y0 * W + x1;
    const int i01 = y1 * W + x0, i11 = y1 * W + x1;

    float* cb = cnt + (size_t)b * HW;
    if (v00) atomicAdd(cb + i00, w00);
    if (v10) atomicAdd(cb + i10, w10);
    if (v01) atomicAdd(cb + i01, w01);
    if (v11) atomicAdd(cb + i11, w11);

    const float* fb = feat + (size_t)b * C * HW;
    float* nb = num + (size_t)b * C * HW;
    const int sp = y * W + x;
    for (int c = 0; c < C; ++c) {
        const float v = fb[(size_t)c * HW + sp];
        if (v00) atomicAdd(nb + (size_t)c * HW + i00, v * w00);
        if (v10) atomicAdd(nb + (size_t)c * HW + i10, v * w10);
        if (v01) atomicAdd(nb + (size_t)c * HW + i01, v * w01);
        if (v11) atomicAdd(nb + (size_t)c * HW + i11, v * w11);
    }
}

// ---------------------------------------------------------------------------
// num /= (cnt == 0 ? 1 : cnt), cnt broadcast over channels
// ---------------------------------------------------------------------------
__global__ void divide_kernel(float* __restrict__ num,
                              const float* __restrict__ cnt,
                              int B, int C, int H, int W) {
    const int HW = H * W;
    const int total = B * C * HW;
    const int idx = blockIdx.x * blockDim.x + threadIdx.x;
    if (idx >= total) return;
    const int hw = idx % HW;
    const int b = idx / (C * HW);
    const float ct = cnt[(size_t)b * HW + hw];
    num[idx] = num[idx] / (ct == 0.f ? 1.f : ct);
}

extern "C" void kernel_launch(void* const* d_in, const int* in_sizes, int n_in,
                              void* d_out, int out_size, void* d_ws, size_t ws_size,
                              hipStream_t stream) {
    (void)in_sizes; (void)n_in; (void)ws_size;

    const float* img  = (const float*)d_in[0];
    const float* flow = (const float*)d_in[1];
    // per-block params: w{i}a, b{i}a, a{i}a, w{i}b, b{i}b, a{i}b at d_in[2+6*(i-1)..]
    const float* P[4][6];
    for (int i = 0; i < 4; ++i)
        for (int j = 0; j < 6; ++j)
            P[i][j] = (const float*)d_in[2 + 6 * i + j];

    const int Bn = 16;
    float* ws = (float*)d_ws;
    float* bufA = ws;                       // 16,777,216 floats (max feat)
    float* bufB = ws + 16777216;            // 16,777,216 floats
    float* flA  = ws + 33554432;            // 2,097,152 floats (flow at 256^2)
    float* flB  = ws + 35651584;            //   524,288 floats (flow at 128^2)
    float* cnt  = ws + 36175872;            // 1,048,576 floats (cnt at 256^2)
    float* out  = (float*)d_out;

    // zero the whole output (splat accumulates into it)
    hipMemsetAsync(d_out, 0, (size_t)out_size * sizeof(float), stream);

    auto conv = [&](const float* in, const float* w, const float* b,
                    const float* a, float* o, int Ci, int Hi, int Wi,
                    int Co, int stride) {
        const int Ho = Hi / stride, Wo = Wi / stride;
        dim3 grid(CDIV(Ho * Wo, 256), Co, Bn);
        hipLaunchKernelGGL(conv3x3_prelu_kernel, grid, dim3(256),
                           Ci * 9 * sizeof(float), stream,
                           in, w, b, a, o, Ci, Hi, Wi, Co, Ho, Wo, stride);
    };
    auto halve = [&](const float* in, float* o, int Hi, int Wi) {
        const int Ho = Hi / 2, Wo = Wi / 2;
        const int total = Bn * 2 * Ho * Wo;
        hipLaunchKernelGGL(halve_flow_kernel, dim3(CDIV(total, 256)), dim3(256),
                           0, stream, in, o, Bn * 2, Ho, Wo, Hi, Wi);
    };
    auto splat_avg = [&](const float* feat, const float* fl, float* o,
                         int C, int H, int W) {
        hipMemsetAsync(cnt, 0, (size_t)Bn * H * W * sizeof(float), stream);
        const int total = Bn * H * W;
        hipLaunchKernelGGL(splat_kernel, dim3(CDIV(total, 256)), dim3(256),
                           0, stream, feat, fl, o, cnt, Bn, C, H, W);
        const int total2 = Bn * C * H * W;
        hipLaunchKernelGGL(divide_kernel, dim3(CDIV(total2, 256)), dim3(256),
                           0, stream, o, cnt, Bn, C, H, W);
    };

    float* p1 = out;
    float* p2 = p1 + (size_t)Bn * 16 * 256 * 256;
    float* p3 = p2 + (size_t)Bn * 32 * 128 * 128;
    float* p4 = p3 + (size_t)Bn * 64 * 64 * 64;

    // ---- level 1: img(3,512) -> feat1(16,256)
    conv(img,  P[0][0], P[0][1], P[0][2], bufA, 3, 512, 512, 16, 2);
    conv(bufA, P[0][3], P[0][4], P[0][5], bufB, 16, 256, 256, 16, 1);
    halve(flow, flA, 512, 512);
    splat_avg(bufB, flA, p1, 16, 256, 256);

    // ---- level 2: feat1(16,256) -> feat2(32,128)
    conv(bufB, P[1][0], P[1][1], P[1][2], bufA, 16, 256, 256, 32, 2);
    conv(bufA, P[1][3], P[1][4], P[1][5], bufB, 32, 128, 128, 32, 1);
    halve(flA, flB, 256, 256);
    splat_avg(bufB, flB, p2, 32, 128, 128);

    // ---- level 3: feat2(32,128) -> feat3(64,64)
    conv(bufB, P[2][0], P[2][1], P[2][2], bufA, 32, 128, 128, 64, 2);
    conv(bufA, P[2][3], P[2][4], P[2][5], bufB, 64, 64, 64, 64, 1);
    halve(flB, flA, 128, 128);
    splat_avg(bufB, flA, p3, 64, 64, 64);

    // ---- level 4: feat3(64,64) -> feat4(128,32)
    conv(bufB, P[3][0], P[3][1], P[3][2], bufA, 64, 64, 64, 128, 2);
    conv(bufA, P[3][3], P[3][4], P[3][5], bufB, 128, 32, 32, 128, 1);
    halve(flA, flB, 64, 64);
    splat_avg(bufB, flB, p4, 128, 32, 32);
}

// Round 2
// 3823.408 us; speedup vs baseline: 2.0665x; 2.0665x over previous
//
#include <hip/hip_runtime.h>

#define CDIV(a, b) (((a) + (b) - 1) / (b))

// ---------------------------------------------------------------------------
// Tiled conv 3x3 pad 1 stride {1,2} + bias + PReLU.
// Block: 256 threads -> 32x32 output tile, KO=8 output channels in registers,
// each thread computes 2x2 pixels for each of the 8 channels.
// Input plane for current ci staged in LDS; weights staged padded (stride 12).
// ---------------------------------------------------------------------------
template <int STRIDE>
__global__ __launch_bounds__(256)
void conv3x3_tile_kernel(const float* __restrict__ in,
                         const float* __restrict__ wgt,
                         const float* __restrict__ bias,
                         const float* __restrict__ alpha,
                         float* __restrict__ out,
                         int Ci, int Hi, int Wi, int Co, int Ho, int Wo,
                         int nTX) {
    constexpr int TS = 32;
    constexpr int IS = TS * STRIDE + 2;   // input tile side
    constexpr int KO = 8;
    constexpr int SP = STRIDE + 3;        // per-thread tap span
    __shared__ float s_in[IS * IS];
    __shared__ float s_w[KO * 12];

    const int b   = blockIdx.z;
    const int co0 = blockIdx.y * KO;
    const int tX  = (blockIdx.x % nTX) * TS;
    const int tY  = (blockIdx.x / nTX) * TS;
    const int t   = threadIdx.x;
    const int tcx = t & 15, tcy = t >> 4;
    const int ox0 = 2 * tcx, oy0 = 2 * tcy;   // local output coords

    float acc[KO][2][2];
#pragma unroll
    for (int ko = 0; ko < KO; ++ko)
#pragma unroll
        for (int dy = 0; dy < 2; ++dy)
#pragma unroll
            for (int dx = 0; dx < 2; ++dx) acc[ko][dy][dx] = 0.f;

    const float* inb = in + (size_t)b * Ci * Hi * Wi;
    const int ix0 = tX * STRIDE - 1, iy0 = tY * STRIDE - 1;

    for (int ci = 0; ci < Ci; ++ci) {
        __syncthreads();
        // stage input plane tile
        const float* inp = inb + (size_t)ci * Hi * Wi;
        for (int i = t; i < IS * IS; i += 256) {
            const int r = i / IS, c = i - r * IS;
            const int gy = iy0 + r, gx = ix0 + c;
            float v = 0.f;
            if (gy >= 0 && gy < Hi && gx >= 0 && gx < Wi)
                v = inp[(size_t)gy * Wi + gx];
            s_in[i] = v;
        }
        // stage weights for this ci (KO x 9, padded to stride 12)
        if (t < KO * 9) {
            const int ko = t / 9, k = t - ko * 9;
            s_w[ko * 12 + k] = wgt[((size_t)(co0 + ko) * Ci + ci) * 9 + k];
        }
        __syncthreads();

        float tap[SP][SP];
#pragma unroll
        for (int r = 0; r < SP; ++r)
#pragma unroll
            for (int c = 0; c < SP; ++c)
                tap[r][c] = s_in[(oy0 * STRIDE + r) * IS + ox0 * STRIDE + c];

#pragma unroll
        for (int ko = 0; ko < KO; ++ko) {
            float w[9];
#pragma unroll
            for (int k = 0; k < 9; ++k) w[k] = s_w[ko * 12 + k];
#pragma unroll
            for (int dy = 0; dy < 2; ++dy)
#pragma unroll
                for (int dx = 0; dx < 2; ++dx) {
                    float a = acc[ko][dy][dx];
#pragma unroll
                    for (int ky = 0; ky < 3; ++ky)
#pragma unroll
                        for (int kx = 0; kx < 3; ++kx)
                            a += tap[dy * STRIDE + ky][dx * STRIDE + kx] *
                                 w[ky * 3 + kx];
                    acc[ko][dy][dx] = a;
                }
        }
    }

    // epilogue: bias + PReLU + store
#pragma unroll
    for (int ko = 0; ko < KO; ++ko) {
        const int co = co0 + ko;
        const float bv = bias[co], av = alpha[co];
#pragma unroll
        for (int dy = 0; dy < 2; ++dy) {
            const int oy = tY + oy0 + dy;
#pragma unroll
            for (int dx = 0; dx < 2; ++dx) {
                const int ox = tX + ox0 + dx;
                float v = acc[ko][dy][dx] + bv;
                v = v >= 0.f ? v : av * v;
                out[(((size_t)b * Co + co) * Ho + oy) * Wo + ox] = v;
            }
        }
    }
}

// ---------------------------------------------------------------------------
// flow halving: 2x2 mean * 0.5 == sum * 0.125
// ---------------------------------------------------------------------------
__global__ void halve_flow_kernel(const float* __restrict__ in,
                                  float* __restrict__ out,
                                  int BC, int Ho, int Wo, int Hi, int Wi) {
    const int idx = blockIdx.x * blockDim.x + threadIdx.x;
    const int total = BC * Ho * Wo;
    if (idx >= total) return;
    const int wo = idx % Wo;
    int t = idx / Wo;
    const int ho = t % Ho;
    const int bc = t / Ho;
    const float* p = in + ((size_t)bc * Hi + 2 * ho) * Wi + 2 * wo;
    out[idx] = (p[0] + p[1] + p[Wi] + p[Wi + 1]) * 0.125f;
}

// ---------------------------------------------------------------------------
// LDS-tiled bilinear forward splat. Block handles a TSxTS source tile of one
// batch; accumulates into an (TS+2R)^2 LDS tile (NCH channels at a time) with
// ds atomics, then flushes with coalesced global atomics (skipping zeros).
// Targets outside the halo fall back to direct global atomics (rare).
// ---------------------------------------------------------------------------
template <int TS, int R, int NCH>
__global__ __launch_bounds__(256)
void splat_tile_kernel(const float* __restrict__ feat,
                       const float* __restrict__ flow,
                       float* __restrict__ num,
                       float* __restrict__ cnt,
                       int C, int H, int W, int nTX) {
    constexpr int ES = TS + 2 * R;
    constexpr int NPX = TS * TS / 256;
    __shared__ float s_acc[NCH * ES * ES];

    const int b = blockIdx.y;
    const int tx0 = (blockIdx.x % nTX) * TS;
    const int ty0 = (blockIdx.x / nTX) * TS;
    const int t = threadIdx.x;
    const int HW = H * W;
    const float* fl = flow + (size_t)b * 2 * HW;

    int   cell[NPX];
    int   cx0[NPX], cy0[NPX];
    float w00[NPX], w10[NPX], w01[NPX], w11[NPX];

#pragma unroll
    for (int p = 0; p < NPX; ++p) {
        const int sp = t + p * 256;
        const int ly = sp / TS, lx = sp - ly * TS;
        const int y = ty0 + ly, x = tx0 + lx;
        const float fx = fl[(size_t)y * W + x] + (float)x;
        const float fy = fl[(size_t)HW + (size_t)y * W + x] + (float)y;
        const float x0f = floorf(fx), y0f = floorf(fy);
        const int x0 = (int)x0f, y0 = (int)y0f;
        const float ax = fx - x0f, ay = fy - y0f;
        float W00 = (1.f - ax) * (1.f - ay);
        float W10 = ax * (1.f - ay);
        float W01 = (1.f - ax) * ay;
        float W11 = ax * ay;
        const bool vx0 = (x0 >= 0) && (x0 < W);
        const bool vx1 = (x0 + 1 >= 0) && (x0 + 1 < W);
        const bool vy0 = (y0 >= 0) && (y0 < H);
        const bool vy1 = (y0 + 1 >= 0) && (y0 + 1 < H);
        if (!(vx0 && vy0)) W00 = 0.f;
        if (!(vx1 && vy0)) W10 = 0.f;
        if (!(vx0 && vy1)) W01 = 0.f;
        if (!(vx1 && vy1)) W11 = 0.f;
        const bool il = (x0 >= tx0 - R) && (x0 < tx0 + TS + R - 1) &&
                        (y0 >= ty0 - R) && (y0 < ty0 + TS + R - 1);
        cell[p] = il ? (y0 - ty0 + R) * ES + (x0 - tx0 + R) : -1;
        cx0[p] = x0; cy0[p] = y0;
        w00[p] = W00; w10[p] = W10; w01[p] = W01; w11[p] = W11;
    }

    // ---- cnt phase (plane 0 of s_acc) ----
    for (int i = t; i < ES * ES; i += 256) s_acc[i] = 0.f;
    __syncthreads();
    float* cb = cnt + (size_t)b * HW;
#pragma unroll
    for (int p = 0; p < NPX; ++p) {
        if (cell[p] >= 0) {
            atomicAdd(&s_acc[cell[p]], w00[p]);
            atomicAdd(&s_acc[cell[p] + 1], w10[p]);
            atomicAdd(&s_acc[cell[p] + ES], w01[p]);
            atomicAdd(&s_acc[cell[p] + ES + 1], w11[p]);
        } else {
            if (w00[p] != 0.f) atomicAdd(cb + (size_t)cy0[p] * W + cx0[p], w00[p]);
            if (w10[p] != 0.f) atomicAdd(cb + (size_t)cy0[p] * W + cx0[p] + 1, w10[p]);
            if (w01[p] != 0.f) atomicAdd(cb + (size_t)(cy0[p] + 1) * W + cx0[p], w01[p]);
            if (w11[p] != 0.f) atomicAdd(cb + (size_t)(cy0[p] + 1) * W + cx0[p] + 1, w11[p]);
        }
    }
    __syncthreads();
    for (int i = t; i < ES * ES; i += 256) {
        const float v = s_acc[i];
        if (v != 0.f) {
            const int r = i / ES, c = i - r * ES;
            const int gy = ty0 - R + r, gx = tx0 - R + c;
            if (gy >= 0 && gy < H && gx >= 0 && gx < W)
                atomicAdd(cb + (size_t)gy * W + gx, v);
        }
    }

    // ---- feature channels, NCH at a time ----
    for (int c0 = 0; c0 < C; c0 += NCH) {
        __syncthreads();
        for (int i = t; i < NCH * ES * ES; i += 256) s_acc[i] = 0.f;
        __syncthreads();
#pragma unroll
        for (int p = 0; p < NPX; ++p) {
            const int sp = t + p * 256;
            const int ly = sp / TS, lx = sp - ly * TS;
            const int y = ty0 + ly, x = tx0 + lx;
            const float* fb = feat + ((size_t)b * C + c0) * HW + (size_t)y * W + x;
            if (cell[p] >= 0) {
#pragma unroll
                for (int ch = 0; ch < NCH; ++ch) {
                    const float f = fb[(size_t)ch * HW];
                    float* pl = s_acc + ch * ES * ES + cell[p];
                    atomicAdd(pl, f * w00[p]);
                    atomicAdd(pl + 1, f * w10[p]);
                    atomicAdd(pl + ES, f * w01[p]);
                    atomicAdd(pl + ES + 1, f * w11[p]);
                }
            } else {
                float* nb = num + ((size_t)b * C + c0) * HW;
#pragma unroll
                for (int ch = 0; ch < NCH; ++ch) {
                    const float f = fb[(size_t)ch * HW];
                    float* q = nb + (size_t)ch * HW;
                    if (w00[p] != 0.f) atomicAdd(q + (size_t)cy0[p] * W + cx0[p], f * w00[p]);
                    if (w10[p] != 0.f) atomicAdd(q + (size_t)cy0[p] * W + cx0[p] + 1, f * w10[p]);
                    if (w01[p] != 0.f) atomicAdd(q + (size_t)(cy0[p] + 1) * W + cx0[p], f * w01[p]);
                    if (w11[p] != 0.f) atomicAdd(q + (size_t)(cy0[p] + 1) * W + cx0[p] + 1, f * w11[p]);
                }
            }
        }
        __syncthreads();
        for (int i = t; i < ES * ES; i += 256) {
            const int r = i / ES, c = i - r * ES;
            const int gy = ty0 - R + r, gx = tx0 - R + c;
            if (gy < 0 || gy >= H || gx < 0 || gx >= W) continue;
            const size_t go = ((size_t)b * C + c0) * HW + (size_t)gy * W + gx;
#pragma unroll
            for (int ch = 0; ch < NCH; ++ch) {
                const float v = s_acc[ch * ES * ES + i];
                if (v != 0.f) atomicAdd(num + go + (size_t)ch * HW, v);
            }
        }
    }
}

// ---------------------------------------------------------------------------
// num /= (cnt == 0 ? 1 : cnt)
// ---------------------------------------------------------------------------
__global__ void divide_kernel(float* __restrict__ num,
                              const float* __restrict__ cnt,
                              int B, int C, int H, int W) {
    const int HW = H * W;
    const int total = B * C * HW;
    const int idx = blockIdx.x * blockDim.x + threadIdx.x;
    if (idx >= total) return;
    const int hw = idx % HW;
    const int b = idx / (C * HW);
    const float ct = cnt[(size_t)b * HW + hw];
    num[idx] = num[idx] / (ct == 0.f ? 1.f : ct);
}

extern "C" void kernel_launch(void* const* d_in, const int* in_sizes, int n_in,
                              void* d_out, int out_size, void* d_ws, size_t ws_size,
                              hipStream_t stream) {
    (void)in_sizes; (void)n_in; (void)ws_size;

    const float* img  = (const float*)d_in[0];
    const float* flow = (const float*)d_in[1];
    const float* P[4][6];
    for (int i = 0; i < 4; ++i)
        for (int j = 0; j < 6; ++j)
            P[i][j] = (const float*)d_in[2 + 6 * i + j];

    const int Bn = 16;
    float* ws = (float*)d_ws;
    float* bufA = ws;                       // 16M floats
    float* bufB = ws + 16777216;            // 16M floats
    float* flA  = ws + 33554432;            // 2M floats
    float* flB  = ws + 35651584;            // 512K floats
    float* cnt  = ws + 36175872;            // 1M floats
    float* out  = (float*)d_out;

    hipMemsetAsync(d_out, 0, (size_t)out_size * sizeof(float), stream);

    auto conv = [&](const float* in, const float* w, const float* b,
                    const float* a, float* o, int Ci, int Hi, int Wi,
                    int Co, int stride) {
        const int Ho = Hi / stride, Wo = Wi / stride;
        const int nTX = Wo / 32, nTY = Ho / 32;
        dim3 grid(nTX * nTY, Co / 8, Bn);
        if (stride == 1)
            hipLaunchKernelGGL(conv3x3_tile_kernel<1>, grid, dim3(256), 0, stream,
                               in, w, b, a, o, Ci, Hi, Wi, Co, Ho, Wo, nTX);
        else
            hipLaunchKernelGGL(conv3x3_tile_kernel<2>, grid, dim3(256), 0, stream,
                               in, w, b, a, o, Ci, Hi, Wi, Co, Ho, Wo, nTX);
    };
    auto halve = [&](const float* in, float* o, int Hi, int Wi) {
        const int Ho = Hi / 2, Wo = Wi / 2;
        const int total = Bn * 2 * Ho * Wo;
        hipLaunchKernelGGL(halve_flow_kernel, dim3(CDIV(total, 256)), dim3(256),
                           0, stream, in, o, Bn * 2, Ho, Wo, Hi, Wi);
    };
    auto splat_avg = [&](const float* feat, const float* fl, float* o,
                         int C, int H, int W) {
        hipMemsetAsync(cnt, 0, (size_t)Bn * H * W * sizeof(float), stream);
        const int nTX = W / 32, nTY = H / 32;
        dim3 grid(nTX * nTY, Bn);
        hipLaunchKernelGGL((splat_tile_kernel<32, 8, 4>), grid, dim3(256),
                           0, stream, feat, fl, o, cnt, C, H, W, nTX);
        const int total2 = Bn * C * H * W;
        hipLaunchKernelGGL(divide_kernel, dim3(CDIV(total2, 256)), dim3(256),
                           0, stream, o, cnt, Bn, C, H, W);
    };

    float* p1 = out;
    float* p2 = p1 + (size_t)Bn * 16 * 256 * 256;
    float* p3 = p2 + (size_t)Bn * 32 * 128 * 128;
    float* p4 = p3 + (size_t)Bn * 64 * 64 * 64;

    // ---- level 1
    conv(img,  P[0][0], P[0][1], P[0][2], bufA, 3, 512, 512, 16, 2);
    conv(bufA, P[0][3], P[0][4], P[0][5], bufB, 16, 256, 256, 16, 1);
    halve(flow, flA, 512, 512);
    splat_avg(bufB, flA, p1, 16, 256, 256);

    // ---- level 2
    conv(bufB, P[1][0], P[1][1], P[1][2], bufA, 16, 256, 256, 32, 2);
    conv(bufA, P[1][3], P[1][4], P[1][5], bufB, 32, 128, 128, 32, 1);
    halve(flA, flB, 256, 256);
    splat_avg(bufB, flB, p2, 32, 128, 128);

    // ---- level 3
    conv(bufB, P[2][0], P[2][1], P[2][2], bufA, 32, 128, 128, 64, 2);
    conv(bufA, P[2][3], P[2][4], P[2][5], bufB, 64, 64, 64, 64, 1);
    halve(flB, flA, 128, 128);
    splat_avg(bufB, flA, p3, 64, 64, 64);

    // ---- level 4
    conv(bufB, P[3][0], P[3][1], P[3][2], bufA, 64, 64, 64, 128, 2);
    conv(bufA, P[3][3], P[3][4], P[3][5], bufB, 128, 32, 32, 128, 1);
    halve(flA, flB, 64, 64);
    splat_avg(bufB, flB, p4, 128, 32, 32);
}

// Round 3
// 2459.492 us; speedup vs baseline: 3.2126x; 1.5546x over previous
//
#include <hip/hip_runtime.h>

#define CDIV(a, b) (((a) + (b) - 1) / (b))

// ---------------------------------------------------------------------------
// Tiled conv 3x3 pad 1 stride {1,2} + bias + PReLU.
// 256 threads -> TSxTS output tile, KO=8 output channels in registers,
// each thread computes (TS/16)^2 pixels. Input plane staged per-ci in LDS.
// ---------------------------------------------------------------------------
template <int STRIDE, int TS>
__global__ __launch_bounds__(256)
void conv3x3_tile_kernel(const float* __restrict__ in,
                         const float* __restrict__ wgt,
                         const float* __restrict__ bias,
                         const float* __restrict__ alpha,
                         float* __restrict__ out,
                         int Ci, int Hi, int Wi, int Co, int Ho, int Wo,
                         int nTX) {
    constexpr int PB = TS / 16;               // pixels per thread per dim
    constexpr int IS = TS * STRIDE + 2;       // input tile side
    constexpr int KO = 8;
    constexpr int SP = (PB - 1) * STRIDE + 3; // per-thread tap span
    __shared__ float s_in[IS * IS];
    __shared__ float s_w[KO * 12];

    const int b   = blockIdx.z;
    const int co0 = blockIdx.y * KO;
    const int tX  = (blockIdx.x % nTX) * TS;
    const int tY  = (blockIdx.x / nTX) * TS;
    const int t   = threadIdx.x;
    const int tcx = t & 15, tcy = t >> 4;
    const int ox0 = PB * tcx, oy0 = PB * tcy;

    float acc[KO][PB][PB];
#pragma unroll
    for (int ko = 0; ko < KO; ++ko)
#pragma unroll
        for (int dy = 0; dy < PB; ++dy)
#pragma unroll
            for (int dx = 0; dx < PB; ++dx) acc[ko][dy][dx] = 0.f;

    const float* inb = in + (size_t)b * Ci * Hi * Wi;
    const int ix0 = tX * STRIDE - 1, iy0 = tY * STRIDE - 1;

    for (int ci = 0; ci < Ci; ++ci) {
        __syncthreads();
        const float* inp = inb + (size_t)ci * Hi * Wi;
        for (int i = t; i < IS * IS; i += 256) {
            const int r = i / IS, c = i - r * IS;
            const int gy = iy0 + r, gx = ix0 + c;
            float v = 0.f;
            if (gy >= 0 && gy < Hi && gx >= 0 && gx < Wi)
                v = inp[(size_t)gy * Wi + gx];
            s_in[i] = v;
        }
        if (t < KO * 9) {
            const int ko = t / 9, k = t - ko * 9;
            s_w[ko * 12 + k] = wgt[((size_t)(co0 + ko) * Ci + ci) * 9 + k];
        }
        __syncthreads();

        float tap[SP][SP];
#pragma unroll
        for (int r = 0; r < SP; ++r)
#pragma unroll
            for (int c = 0; c < SP; ++c)
                tap[r][c] = s_in[(oy0 * STRIDE + r) * IS + ox0 * STRIDE + c];

#pragma unroll
        for (int ko = 0; ko < KO; ++ko) {
            float w[9];
#pragma unroll
            for (int k = 0; k < 9; ++k) w[k] = s_w[ko * 12 + k];
#pragma unroll
            for (int dy = 0; dy < PB; ++dy)
#pragma unroll
                for (int dx = 0; dx < PB; ++dx) {
                    float a = acc[ko][dy][dx];
#pragma unroll
                    for (int ky = 0; ky < 3; ++ky)
#pragma unroll
                        for (int kx = 0; kx < 3; ++kx)
                            a += tap[dy * STRIDE + ky][dx * STRIDE + kx] *
                                 w[ky * 3 + kx];
                    acc[ko][dy][dx] = a;
                }
        }
    }

#pragma unroll
    for (int ko = 0; ko < KO; ++ko) {
        const int co = co0 + ko;
        const float bv = bias[co], av = alpha[co];
#pragma unroll
        for (int dy = 0; dy < PB; ++dy) {
            const int oy = tY + oy0 + dy;
#pragma unroll
            for (int dx = 0; dx < PB; ++dx) {
                const int ox = tX + ox0 + dx;
                float v = acc[ko][dy][dx] + bv;
                v = v >= 0.f ? v : av * v;
                out[(((size_t)b * Co + co) * Ho + oy) * Wo + ox] = v;
            }
        }
    }
}

// ---------------------------------------------------------------------------
// flow halving: 2x2 mean * 0.5 == sum * 0.125
// ---------------------------------------------------------------------------
__global__ void halve_flow_kernel(const float* __restrict__ in,
                                  float* __restrict__ out,
                                  int BC, int Ho, int Wo, int Hi, int Wi) {
    const int idx = blockIdx.x * blockDim.x + threadIdx.x;
    const int total = BC * Ho * Wo;
    if (idx >= total) return;
    const int wo = idx % Wo;
    int t = idx / Wo;
    const int ho = t % Ho;
    const int bc = t / Ho;
    const float* p = in + ((size_t)bc * Hi + 2 * ho) * Wi + 2 * wo;
    out[idx] = (p[0] + p[1] + p[Wi] + p[Wi + 1]) * 0.125f;
}

// ---------------------------------------------------------------------------
// splat weight helper (shared by cnt/feat kernels)
// ---------------------------------------------------------------------------
struct SplatPx {
    int cell;           // LDS cell index, or -1 if outside halo
    int x0, y0;
    float w00, w10, w01, w11;
};

template <int TS, int R>
__device__ inline SplatPx splat_px(const float* fl, int HW, int x, int y,
                                   int tx0, int ty0, int H, int W) {
    constexpr int ES = TS + 2 * R;
    SplatPx s;
    const float fx = fl[(size_t)y * W + x] + (float)x;
    const float fy = fl[(size_t)HW + (size_t)y * W + x] + (float)y;
    const float x0f = floorf(fx), y0f = floorf(fy);
    s.x0 = (int)x0f; s.y0 = (int)y0f;
    const float ax = fx - x0f, ay = fy - y0f;
    s.w00 = (1.f - ax) * (1.f - ay);
    s.w10 = ax * (1.f - ay);
    s.w01 = (1.f - ax) * ay;
    s.w11 = ax * ay;
    const bool vx0 = (s.x0 >= 0) && (s.x0 < W);
    const bool vx1 = (s.x0 + 1 >= 0) && (s.x0 + 1 < W);
    const bool vy0 = (s.y0 >= 0) && (s.y0 < H);
    const bool vy1 = (s.y0 + 1 >= 0) && (s.y0 + 1 < H);
    if (!(vx0 && vy0)) s.w00 = 0.f;
    if (!(vx1 && vy0)) s.w10 = 0.f;
    if (!(vx0 && vy1)) s.w01 = 0.f;
    if (!(vx1 && vy1)) s.w11 = 0.f;
    const bool il = (s.x0 >= tx0 - R) && (s.x0 < tx0 + TS + R - 1) &&
                    (s.y0 >= ty0 - R) && (s.y0 < ty0 + TS + R - 1);
    s.cell = il ? (s.y0 - ty0 + R) * ES + (s.x0 - tx0 + R) : -1;
    return s;
}

// ---------------------------------------------------------------------------
// cnt splat: grid (tiles, B)
// ---------------------------------------------------------------------------
template <int TS, int R>
__global__ __launch_bounds__(256)
void splat_cnt_kernel(const float* __restrict__ flow,
                      float* __restrict__ cnt,
                      int H, int W, int nTX) {
    constexpr int ES = TS + 2 * R;
    constexpr int NPX = TS * TS / 256;
    __shared__ float s_acc[ES * ES];
    const int b = blockIdx.y;
    const int tx0 = (blockIdx.x % nTX) * TS;
    const int ty0 = (blockIdx.x / nTX) * TS;
    const int t = threadIdx.x;
    const int HW = H * W;
    const float* fl = flow + (size_t)b * 2 * HW;
    float* cb = cnt + (size_t)b * HW;

    for (int i = t; i < ES * ES; i += 256) s_acc[i] = 0.f;
    __syncthreads();

#pragma unroll
    for (int p = 0; p < NPX; ++p) {
        const int sp = t + p * 256;
        const int ly = sp / TS, lx = sp - ly * TS;
        const SplatPx s = splat_px<TS, R>(fl, HW, tx0 + lx, ty0 + ly, tx0, ty0, H, W);
        if (s.cell >= 0) {
            atomicAdd(&s_acc[s.cell], s.w00);
            atomicAdd(&s_acc[s.cell + 1], s.w10);
            atomicAdd(&s_acc[s.cell + ES], s.w01);
            atomicAdd(&s_acc[s.cell + ES + 1], s.w11);
        } else {
            if (s.w00 != 0.f) atomicAdd(cb + (size_t)s.y0 * W + s.x0, s.w00);
            if (s.w10 != 0.f) atomicAdd(cb + (size_t)s.y0 * W + s.x0 + 1, s.w10);
            if (s.w01 != 0.f) atomicAdd(cb + (size_t)(s.y0 + 1) * W + s.x0, s.w01);
            if (s.w11 != 0.f) atomicAdd(cb + (size_t)(s.y0 + 1) * W + s.x0 + 1, s.w11);
        }
    }
    __syncthreads();
    for (int i = t; i < ES * ES; i += 256) {
        const float v = s_acc[i];
        if (v != 0.f) {
            const int r = i / ES, c = i - r * ES;
            const int gy = ty0 - R + r, gx = tx0 - R + c;
            if (gy >= 0 && gy < H && gx >= 0 && gx < W)
                atomicAdd(cb + (size_t)gy * W + gx, v);
        }
    }
}

// ---------------------------------------------------------------------------
// feature splat: grid (tiles, C/NCH, B) — channel chunks run in parallel
// ---------------------------------------------------------------------------
template <int TS, int R, int NCH>
__global__ __launch_bounds__(256)
void splat_feat_kernel(const float* __restrict__ feat,
                       const float* __restrict__ flow,
                       float* __restrict__ num,
                       int C, int H, int W, int nTX) {
    constexpr int ES = TS + 2 * R;
    constexpr int NPX = TS * TS / 256;
    __shared__ float s_acc[NCH * ES * ES];
    const int b  = blockIdx.z;
    const int c0 = blockIdx.y * NCH;
    const int tx0 = (blockIdx.x % nTX) * TS;
    const int ty0 = (blockIdx.x / nTX) * TS;
    const int t = threadIdx.x;
    const int HW = H * W;
    const float* fl = flow + (size_t)b * 2 * HW;

    for (int i = t; i < NCH * ES * ES; i += 256) s_acc[i] = 0.f;
    __syncthreads();

#pragma unroll
    for (int p = 0; p < NPX; ++p) {
        const int sp = t + p * 256;
        const int ly = sp / TS, lx = sp - ly * TS;
        const int y = ty0 + ly, x = tx0 + lx;
        const SplatPx s = splat_px<TS, R>(fl, HW, x, y, tx0, ty0, H, W);
        const float* fb = feat + ((size_t)b * C + c0) * HW + (size_t)y * W + x;
        if (s.cell >= 0) {
#pragma unroll
            for (int ch = 0; ch < NCH; ++ch) {
                const float f = fb[(size_t)ch * HW];
                float* pl = s_acc + ch * ES * ES + s.cell;
                atomicAdd(pl, f * s.w00);
                atomicAdd(pl + 1, f * s.w10);
                atomicAdd(pl + ES, f * s.w01);
                atomicAdd(pl + ES + 1, f * s.w11);
            }
        } else {
            float* nb = num + ((size_t)b * C + c0) * HW;
#pragma unroll
            for (int ch = 0; ch < NCH; ++ch) {
                const float f = fb[(size_t)ch * HW];
                float* q = nb + (size_t)ch * HW;
                if (s.w00 != 0.f) atomicAdd(q + (size_t)s.y0 * W + s.x0, f * s.w00);
                if (s.w10 != 0.f) atomicAdd(q + (size_t)s.y0 * W + s.x0 + 1, f * s.w10);
                if (s.w01 != 0.f) atomicAdd(q + (size_t)(s.y0 + 1) * W + s.x0, f * s.w01);
                if (s.w11 != 0.f) atomicAdd(q + (size_t)(s.y0 + 1) * W + s.x0 + 1, f * s.w11);
            }
        }
    }
    __syncthreads();
    for (int i = t; i < ES * ES; i += 256) {
        const int r = i / ES, c = i - r * ES;
        const int gy = ty0 - R + r, gx = tx0 - R + c;
        if (gy < 0 || gy >= H || gx < 0 || gx >= W) continue;
        const size_t go = ((size_t)b * C + c0) * HW + (size_t)gy * W + gx;
#pragma unroll
        for (int ch = 0; ch < NCH; ++ch) {
            const float v = s_acc[ch * ES * ES + i];
            if (v != 0.f) atomicAdd(num + go + (size_t)ch * HW, v);
        }
    }
}

// ---------------------------------------------------------------------------
// num /= (cnt == 0 ? 1 : cnt)
// ---------------------------------------------------------------------------
__global__ void divide_kernel(float* __restrict__ num,
                              const float* __restrict__ cnt,
                              int B, int C, int H, int W) {
    const int HW = H * W;
    const int total = B * C * HW;
    const int idx = blockIdx.x * blockDim.x + threadIdx.x;
    if (idx >= total) return;
    const int hw = idx % HW;
    const int b = idx / (C * HW);
    const float ct = cnt[(size_t)b * HW + hw];
    num[idx] = num[idx] / (ct == 0.f ? 1.f : ct);
}

extern "C" void kernel_launch(void* const* d_in, const int* in_sizes, int n_in,
                              void* d_out, int out_size, void* d_ws, size_t ws_size,
                              hipStream_t stream) {
    (void)in_sizes; (void)n_in; (void)ws_size;

    const float* img  = (const float*)d_in[0];
    const float* flow = (const float*)d_in[1];
    const float* P[4][6];
    for (int i = 0; i < 4; ++i)
        for (int j = 0; j < 6; ++j)
            P[i][j] = (const float*)d_in[2 + 6 * i + j];

    const int Bn = 16;
    float* ws = (float*)d_ws;
    float* bufA = ws;                       // 16M floats
    float* bufB = ws + 16777216;            // 16M floats
    float* flA  = ws + 33554432;            // 2M floats
    float* flB  = ws + 35651584;            // 512K floats
    float* cnt  = ws + 36175872;            // 1M floats
    float* out  = (float*)d_out;

    hipMemsetAsync(d_out, 0, (size_t)out_size * sizeof(float), stream);

    auto conv = [&](const float* in, const float* w, const float* b,
                    const float* a, float* o, int Ci, int Hi, int Wi,
                    int Co, int stride) {
        const int Ho = Hi / stride, Wo = Wi / stride;
        const int TS = (Wo >= 128) ? 32 : 16;
        const int nTX = Wo / TS, nTY = Ho / TS;
        dim3 grid(nTX * nTY, Co / 8, Bn);
        if (stride == 1) {
            if (TS == 32)
                hipLaunchKernelGGL((conv3x3_tile_kernel<1, 32>), grid, dim3(256), 0,
                                   stream, in, w, b, a, o, Ci, Hi, Wi, Co, Ho, Wo, nTX);
            else
                hipLaunchKernelGGL((conv3x3_tile_kernel<1, 16>), grid, dim3(256), 0,
                                   stream, in, w, b, a, o, Ci, Hi, Wi, Co, Ho, Wo, nTX);
        } else {
            if (TS == 32)
                hipLaunchKernelGGL((conv3x3_tile_kernel<2, 32>), grid, dim3(256), 0,
                                   stream, in, w, b, a, o, Ci, Hi, Wi, Co, Ho, Wo, nTX);
            else
                hipLaunchKernelGGL((conv3x3_tile_kernel<2, 16>), grid, dim3(256), 0,
                                   stream, in, w, b, a, o, Ci, Hi, Wi, Co, Ho, Wo, nTX);
        }
    };
    auto halve = [&](const float* in, float* o, int Hi, int Wi) {
        const int Ho = Hi / 2, Wo = Wi / 2;
        const int total = Bn * 2 * Ho * Wo;
        hipLaunchKernelGGL(halve_flow_kernel, dim3(CDIV(total, 256)), dim3(256),
                           0, stream, in, o, Bn * 2, Ho, Wo, Hi, Wi);
    };
    auto splat_avg = [&](const float* feat, const float* fl, float* o,
                         int C, int H, int W) {
        hipMemsetAsync(cnt, 0, (size_t)Bn * H * W * sizeof(float), stream);
        constexpr int NCH = 4;
        if (W >= 128) {
            const int nTX = W / 32, nTY = H / 32;
            hipLaunchKernelGGL((splat_cnt_kernel<32, 8>), dim3(nTX * nTY, Bn),
                               dim3(256), 0, stream, fl, cnt, H, W, nTX);
            hipLaunchKernelGGL((splat_feat_kernel<32, 8, NCH>),
                               dim3(nTX * nTY, C / NCH, Bn), dim3(256), 0, stream,
                               feat, fl, o, C, H, W, nTX);
        } else {
            const int nTX = W / 16, nTY = H / 16;
            hipLaunchKernelGGL((splat_cnt_kernel<16, 4>), dim3(nTX * nTY, Bn),
                               dim3(256), 0, stream, fl, cnt, H, W, nTX);
            hipLaunchKernelGGL((splat_feat_kernel<16, 4, NCH>),
                               dim3(nTX * nTY, C / NCH, Bn), dim3(256), 0, stream,
                               feat, fl, o, C, H, W, nTX);
        }
        const int total2 = Bn * C * H * W;
        hipLaunchKernelGGL(divide_kernel, dim3(CDIV(total2, 256)), dim3(256),
                           0, stream, o, cnt, Bn, C, H, W);
    };

    float* p1 = out;
    float* p2 = p1 + (size_t)Bn * 16 * 256 * 256;
    float* p3 = p2 + (size_t)Bn * 32 * 128 * 128;
    float* p4 = p3 + (size_t)Bn * 64 * 64 * 64;

    // ---- level 1
    conv(img,  P[0][0], P[0][1], P[0][2], bufA, 3, 512, 512, 16, 2);
    conv(bufA, P[0][3], P[0][4], P[0][5], bufB, 16, 256, 256, 16, 1);
    halve(flow, flA, 512, 512);
    splat_avg(bufB, flA, p1, 16, 256, 256);

    // ---- level 2
    conv(bufB, P[1][0], P[1][1], P[1][2], bufA, 16, 256, 256, 32, 2);
    conv(bufA, P[1][3], P[1][4], P[1][5], bufB, 32, 128, 128, 32, 1);
    halve(flA, flB, 256, 256);
    splat_avg(bufB, flB, p2, 32, 128, 128);

    // ---- level 3
    conv(bufB, P[2][0], P[2][1], P[2][2], bufA, 32, 128, 128, 64, 2);
    conv(bufA, P[2][3], P[2][4], P[2][5], bufB, 64, 64, 64, 64, 1);
    halve(flB, flA, 128, 128);
    splat_avg(bufB, flA, p3, 64, 64, 64);

    // ---- level 4
    conv(bufB, P[3][0], P[3][1], P[3][2], bufA, 64, 64, 64, 128, 2);
    conv(bufA, P[3][3], P[3][4], P[3][5], bufB, 128, 32, 32, 128, 1);
    halve(flA, flB, 64, 64);
    splat_avg(bufB, flB, p4, 128, 32, 32);
}